// Round 9
// baseline (753.245 us; speedup 1.0000x reference)
//
#include <hip/hip_runtime.h>

#define D 128
#define BM 64        // rows per gemm block
#define NB1 128      // binning blocks
#define BINSH 6      // 64 rows per bin
#define MAXBINS 1024
#define CAPB 1536    // entries per bin segment (avg 1023, +16 sigma)

typedef __attribute__((ext_vector_type(8))) short bf16x8;
typedef __attribute__((ext_vector_type(4))) float f32x4;

__device__ __forceinline__ unsigned short f2bf(float f) {
    unsigned u = __float_as_uint(f);
    u = (u + 0x7FFFu + ((u >> 16) & 1u)) >> 16;   // RNE
    return (unsigned short)u;
}
__device__ __forceinline__ float bf2f(unsigned short h) {
    return __uint_as_float(((unsigned)h) << 16);
}

// ---------------- prep: Wt[n][k] = bf16(W[k][n]) + zero bin counters ----------------
__global__ __launch_bounds__(128) void k_prepw(const float* __restrict__ W,
                                               unsigned short* __restrict__ Wt,
                                               int* __restrict__ gcnt, int nbins) {
    int nn = blockIdx.x, k = threadIdx.x;
    Wt[nn * D + k] = f2bf(W[k * D + nn]);
    int gtid = blockIdx.x * 128 + threadIdx.x;
    for (int i = gtid; i < nbins * 16; i += 128 * D) gcnt[i] = 0;
}

// ---------------- GEMM: HWb = bf16(bf16(H) @ bf16(W)) via MFMA ----------------
__global__ __launch_bounds__(256) void k_gemm(const float* __restrict__ H,
                                              const unsigned short* __restrict__ Wt,
                                              unsigned short* __restrict__ HWb,
                                              int n) {
    __shared__ unsigned short sA[BM * D];
    __shared__ unsigned short sB[D * D];
    const int tid = threadIdx.x;
    const int row0 = blockIdx.x * BM;

#pragma unroll
    for (int s = 0; s < 8; ++s) {
        int idx = s * 256 + tid;
        int nn = idx >> 4, cc = idx & 15;
        bf16x8 v = *reinterpret_cast<const bf16x8*>(&Wt[(size_t)idx * 8]);
        *reinterpret_cast<bf16x8*>(&sB[nn * D + ((cc ^ (nn & 7)) * 8)]) = v;
    }
#pragma unroll
    for (int s = 0; s < 4; ++s) {
        int idx = s * 256 + tid;
        int r = idx >> 4, cc = idx & 15;
        int row = row0 + r;
        float4 u0 = make_float4(0.f, 0.f, 0.f, 0.f), u1 = u0;
        if (row < n) {
            const float4* p = reinterpret_cast<const float4*>(&H[(size_t)row * D + cc * 8]);
            u0 = p[0]; u1 = p[1];
        }
        bf16x8 v;
        v[0] = (short)f2bf(u0.x); v[1] = (short)f2bf(u0.y);
        v[2] = (short)f2bf(u0.z); v[3] = (short)f2bf(u0.w);
        v[4] = (short)f2bf(u1.x); v[5] = (short)f2bf(u1.y);
        v[6] = (short)f2bf(u1.z); v[7] = (short)f2bf(u1.w);
        *reinterpret_cast<bf16x8*>(&sA[r * D + ((cc ^ (r & 7)) * 8)]) = v;
    }
    __syncthreads();

    const int w = tid >> 6, l = tid & 63;
    const int lr = l & 15, lq = l >> 4;
    f32x4 acc[8];
#pragma unroll
    for (int ct = 0; ct < 8; ++ct) acc[ct] = (f32x4){0.f, 0.f, 0.f, 0.f};

#pragma unroll
    for (int ks = 0; ks < 4; ++ks) {
        const int arow = w * 16 + lr;
        const int acc_c = (ks * 4 + lq) ^ (arow & 7);
        bf16x8 a = *reinterpret_cast<const bf16x8*>(&sA[arow * D + acc_c * 8]);
#pragma unroll
        for (int ct = 0; ct < 8; ++ct) {
            const int brow = ct * 16 + lr;
            const int bcc = (ks * 4 + lq) ^ (brow & 7);
            bf16x8 b = *reinterpret_cast<const bf16x8*>(&sB[brow * D + bcc * 8]);
            acc[ct] = __builtin_amdgcn_mfma_f32_16x16x32_bf16(a, b, acc[ct], 0, 0, 0);
        }
    }

#pragma unroll
    for (int ct = 0; ct < 8; ++ct) {
#pragma unroll
        for (int i = 0; i < 4; ++i) {
            int row = row0 + w * 16 + lq * 4 + i;
            int col = ct * 16 + lr;
            if (row < n) HWb[(size_t)row * D + col] = f2bf(acc[ct][i]);
        }
    }
}

// ---------------- pass 1: bin edges into per-bin segments ----------------
// Block takes a contiguous edge chunk; counts per bin in LDS; reserves a
// contiguous slice of each bin's segment with ONE global atomic per
// (block,bin); re-reads the chunk and writes packed 8B entries in bursts
// (avg 8 entries = one 64B line per block per bin -> ~no write amplification).
// Entry: x = (row_in_bin << 16) | col  (requires n < 65536), y = val bits.
__global__ __launch_bounds__(256) void k_bin(const int* __restrict__ rows,
                                             const int* __restrict__ cols,
                                             const float* __restrict__ vals,
                                             int* __restrict__ gcnt,
                                             int2* __restrict__ segs,
                                             int E, int nbins) {
    __shared__ int lcnt[MAXBINS];
    __shared__ int loff[MAXBINS];
    int chunk = (E + NB1 - 1) / NB1;
    int s = blockIdx.x * chunk;
    int epos = s + chunk; if (epos > E) epos = E;
    for (int i = threadIdx.x; i < nbins; i += 256) lcnt[i] = 0;
    __syncthreads();
    for (int e = s + threadIdx.x; e < epos; e += 256)
        atomicAdd(&lcnt[rows[e] >> BINSH], 1);
    __syncthreads();
    for (int i = threadIdx.x; i < nbins; i += 256) {
        int c = lcnt[i];
        int base = c ? atomicAdd(&gcnt[i * 16], c) : 0;
        loff[i] = i * CAPB + base;
        lcnt[i] = 0;                    // reuse as cursor
    }
    __syncthreads();
    for (int e = s + threadIdx.x; e < epos; e += 256) {
        int r = rows[e];
        int c = cols[e];
        float v = vals[e];
        int bin = r >> BINSH;
        int p = atomicAdd(&lcnt[bin], 1);
        int pos = loff[bin] + p;
        if (pos < (bin + 1) * CAPB)     // overflow guard (won't trigger)
            segs[pos] = make_int2(((r & 63) << 16) | c, __float_as_int(v));
    }
}

// ---------------- pass 2: per-bin SpMM with LDS fp32 accumulators ----------------
// One block per 64-row bin; gathers HWb rows for the bin's edges, accumulates
// into 32KB LDS via atomicAdd (2-way bank alias = free), then writes
// bias+ReLU output directly. Replaces bucket+gather entirely.
__global__ __launch_bounds__(256) void k_spmm(const unsigned short* __restrict__ HWb,
                                              const int* __restrict__ gcnt,
                                              const int2* __restrict__ segs,
                                              const float* __restrict__ bias,
                                              float* __restrict__ out, int n) {
    __shared__ float acc[64 * D];      // 32KB
    const int b = blockIdx.x;
    for (int i = threadIdx.x; i < 64 * D; i += 256) acc[i] = 0.f;
    __syncthreads();

    int cnt = gcnt[b * 16];
    if (cnt > CAPB) cnt = CAPB;
    const int2* seg = segs + (size_t)b * CAPB;
    const int w = threadIdx.x >> 6, lane = threadIdx.x & 63;
    const unsigned c2 = 2 * lane;

    for (int base = w * 64; base < cnt; base += 256) {
        int m = cnt - base; if (m > 64) m = 64;
        int2 ent = (lane < m) ? seg[base + lane] : make_int2(0, 0);
        int t = 0;
        for (; t + 4 <= m; t += 4) {
            int x0 = __shfl(ent.x, t);     float v0 = __int_as_float(__shfl(ent.y, t));
            int x1 = __shfl(ent.x, t + 1); float v1 = __int_as_float(__shfl(ent.y, t + 1));
            int x2 = __shfl(ent.x, t + 2); float v2 = __int_as_float(__shfl(ent.y, t + 2));
            int x3 = __shfl(ent.x, t + 3); float v3 = __int_as_float(__shfl(ent.y, t + 3));
            unsigned m0 = *reinterpret_cast<const unsigned*>(&HWb[(size_t)(x0 & 0xFFFF) * D + c2]);
            unsigned m1 = *reinterpret_cast<const unsigned*>(&HWb[(size_t)(x1 & 0xFFFF) * D + c2]);
            unsigned m2 = *reinterpret_cast<const unsigned*>(&HWb[(size_t)(x2 & 0xFFFF) * D + c2]);
            unsigned m3 = *reinterpret_cast<const unsigned*>(&HWb[(size_t)(x3 & 0xFFFF) * D + c2]);
            int r0 = ((unsigned)x0 >> 16) * D, r1 = ((unsigned)x1 >> 16) * D;
            int r2 = ((unsigned)x2 >> 16) * D, r3 = ((unsigned)x3 >> 16) * D;
            atomicAdd(&acc[r0 + c2],     v0 * bf2f((unsigned short)(m0 & 0xFFFF)));
            atomicAdd(&acc[r0 + c2 + 1], v0 * bf2f((unsigned short)(m0 >> 16)));
            atomicAdd(&acc[r1 + c2],     v1 * bf2f((unsigned short)(m1 & 0xFFFF)));
            atomicAdd(&acc[r1 + c2 + 1], v1 * bf2f((unsigned short)(m1 >> 16)));
            atomicAdd(&acc[r2 + c2],     v2 * bf2f((unsigned short)(m2 & 0xFFFF)));
            atomicAdd(&acc[r2 + c2 + 1], v2 * bf2f((unsigned short)(m2 >> 16)));
            atomicAdd(&acc[r3 + c2],     v3 * bf2f((unsigned short)(m3 & 0xFFFF)));
            atomicAdd(&acc[r3 + c2 + 1], v3 * bf2f((unsigned short)(m3 >> 16)));
        }
        for (; t < m; ++t) {
            int x = __shfl(ent.x, t);
            float v = __int_as_float(__shfl(ent.y, t));
            unsigned mm = *reinterpret_cast<const unsigned*>(&HWb[(size_t)(x & 0xFFFF) * D + c2]);
            int rr = ((unsigned)x >> 16) * D;
            atomicAdd(&acc[rr + c2],     v * bf2f((unsigned short)(mm & 0xFFFF)));
            atomicAdd(&acc[rr + c2 + 1], v * bf2f((unsigned short)(mm >> 16)));
        }
    }
    __syncthreads();

    const float2* acc2 = reinterpret_cast<const float2*>(acc);
    const float2* bias2 = reinterpret_cast<const float2*>(bias);
    for (int j = threadIdx.x; j < 64 * (D / 2); j += 256) {
        int row = b * 64 + (j >> 6);
        if (row < n) {
            float2 a = acc2[j];
            float2 bb = bias2[j & 63];
            float2 o;
            o.x = fmaxf(a.x + bb.x, 0.f);
            o.y = fmaxf(a.y + bb.y, 0.f);
            reinterpret_cast<float2*>(out)[(size_t)row * (D / 2) + (j & 63)] = o;
        }
    }
}

// ---------------- Fallback path (small ws): atomic scatter ----------------
__global__ void k_init_bias(const float* __restrict__ bias, float* __restrict__ out, int n) {
    int i = blockIdx.x * blockDim.x + threadIdx.x;
    if (i < n * D) out[i] = bias[i & (D - 1)];
}
__global__ void k_scatter(const unsigned short* __restrict__ HWb, const int* __restrict__ rows,
                          const int* __restrict__ cols, const float* __restrict__ vals,
                          float* __restrict__ out, int E) {
    int e = blockIdx.x * 2 + (threadIdx.x >> 7);
    int j = threadIdx.x & (D - 1);
    if (e < E) {
        int r = rows[e];
        int c = cols[e];
        float v = vals[e];
        atomicAdd(&out[(size_t)r * D + j], v * bf2f(HWb[(size_t)c * D + j]));
    }
}
__global__ void k_relu(float* __restrict__ out, int n) {
    int i = blockIdx.x * blockDim.x + threadIdx.x;
    if (i < n * D) out[i] = fmaxf(out[i], 0.f);
}

extern "C" void kernel_launch(void* const* d_in, const int* in_sizes, int n_in,
                              void* d_out, int out_size, void* d_ws, size_t ws_size,
                              hipStream_t stream) {
    const float* H         = (const float*)d_in[0];
    const float* W         = (const float*)d_in[1];
    const float* bias      = (const float*)d_in[2];
    const float* edge_vals = (const float*)d_in[3];
    const int*   edge_rows = (const int*)d_in[4];
    const int*   edge_cols = (const int*)d_in[5];
    float* out = (float*)d_out;

    const int n = in_sizes[0] / D;   // 50000
    const int E = in_sizes[3];       // 800000
    const int gblocks = (n + BM - 1) / BM;
    const int nbins = (n + 63) >> BINSH;   // 782

    char* ws = (char*)d_ws;
    unsigned short* HWb = (unsigned short*)ws; ws += (size_t)n * D * sizeof(unsigned short);
    unsigned short* Wt  = (unsigned short*)ws; ws += (size_t)D * D * sizeof(unsigned short);
    int* gcnt = (int*)ws;            ws += (size_t)nbins * 16 * sizeof(int);
    int2* segs = (int2*)ws;          ws += (size_t)nbins * CAPB * sizeof(int2);
    size_t need_full = (size_t)(ws - (char*)d_ws);

    k_prepw<<<D, D, 0, stream>>>(W, Wt, gcnt, nbins);
    k_gemm<<<gblocks, 256, 0, stream>>>(H, Wt, HWb, n);

    if (ws_size >= need_full && n < 65536 && nbins <= MAXBINS) {
        k_bin<<<NB1, 256, 0, stream>>>(edge_rows, edge_cols, edge_vals,
                                       gcnt, segs, E, nbins);
        k_spmm<<<nbins, 256, 0, stream>>>(HWb, gcnt, segs, bias, out, n);
    } else {
        k_init_bias<<<((size_t)n * D + 255) / 256, 256, 0, stream>>>(bias, out, n);
        k_scatter<<<(E + 1) / 2, 256, 0, stream>>>(HWb, edge_rows, edge_cols, edge_vals, out, E);
        k_relu<<<((size_t)n * D + 255) / 256, 256, 0, stream>>>(out, n);
    }
}

// Round 10
// 89.585 us; speedup vs baseline: 8.4081x; 8.4081x over previous
//
#include <hip/hip_runtime.h>

#define D 128
#define BM 64        // rows per gemm block
#define NB1 128      // binning blocks
#define BINSH 6      // 64 rows per bin
#define MAXBINS 1024
#define CAPB 1536    // entries per bin segment (avg 1023, +16 sigma)

typedef __attribute__((ext_vector_type(8))) short bf16x8;
typedef __attribute__((ext_vector_type(4))) float f32x4;

__device__ __forceinline__ unsigned short f2bf(float f) {
    unsigned u = __float_as_uint(f);
    u = (u + 0x7FFFu + ((u >> 16) & 1u)) >> 16;   // RNE
    return (unsigned short)u;
}
__device__ __forceinline__ float bf2f(unsigned short h) {
    return __uint_as_float(((unsigned)h) << 16);
}

// ---------------- prep: Wt[n][k] = bf16(W[k][n]) + zero bin counters ----------------
__global__ __launch_bounds__(128) void k_prepw(const float* __restrict__ W,
                                               unsigned short* __restrict__ Wt,
                                               int* __restrict__ gcnt, int nbins) {
    int nn = blockIdx.x, k = threadIdx.x;
    Wt[nn * D + k] = f2bf(W[k * D + nn]);
    int gtid = blockIdx.x * 128 + threadIdx.x;
    for (int i = gtid; i < nbins * 16; i += 128 * D) gcnt[i] = 0;
}

// ---------------- GEMM: HWb = bf16(bf16(H) @ bf16(W)) via MFMA ----------------
__global__ __launch_bounds__(256) void k_gemm(const float* __restrict__ H,
                                              const unsigned short* __restrict__ Wt,
                                              unsigned short* __restrict__ HWb,
                                              int n) {
    __shared__ unsigned short sA[BM * D];
    __shared__ unsigned short sB[D * D];
    const int tid = threadIdx.x;
    const int row0 = blockIdx.x * BM;

#pragma unroll
    for (int s = 0; s < 8; ++s) {
        int idx = s * 256 + tid;
        int nn = idx >> 4, cc = idx & 15;
        bf16x8 v = *reinterpret_cast<const bf16x8*>(&Wt[(size_t)idx * 8]);
        *reinterpret_cast<bf16x8*>(&sB[nn * D + ((cc ^ (nn & 7)) * 8)]) = v;
    }
#pragma unroll
    for (int s = 0; s < 4; ++s) {
        int idx = s * 256 + tid;
        int r = idx >> 4, cc = idx & 15;
        int row = row0 + r;
        float4 u0 = make_float4(0.f, 0.f, 0.f, 0.f), u1 = u0;
        if (row < n) {
            const float4* p = reinterpret_cast<const float4*>(&H[(size_t)row * D + cc * 8]);
            u0 = p[0]; u1 = p[1];
        }
        bf16x8 v;
        v[0] = (short)f2bf(u0.x); v[1] = (short)f2bf(u0.y);
        v[2] = (short)f2bf(u0.z); v[3] = (short)f2bf(u0.w);
        v[4] = (short)f2bf(u1.x); v[5] = (short)f2bf(u1.y);
        v[6] = (short)f2bf(u1.z); v[7] = (short)f2bf(u1.w);
        *reinterpret_cast<bf16x8*>(&sA[r * D + ((cc ^ (r & 7)) * 8)]) = v;
    }
    __syncthreads();

    const int w = tid >> 6, l = tid & 63;
    const int lr = l & 15, lq = l >> 4;
    f32x4 acc[8];
#pragma unroll
    for (int ct = 0; ct < 8; ++ct) acc[ct] = (f32x4){0.f, 0.f, 0.f, 0.f};

#pragma unroll
    for (int ks = 0; ks < 4; ++ks) {
        const int arow = w * 16 + lr;
        const int acc_c = (ks * 4 + lq) ^ (arow & 7);
        bf16x8 a = *reinterpret_cast<const bf16x8*>(&sA[arow * D + acc_c * 8]);
#pragma unroll
        for (int ct = 0; ct < 8; ++ct) {
            const int brow = ct * 16 + lr;
            const int bcc = (ks * 4 + lq) ^ (brow & 7);
            bf16x8 b = *reinterpret_cast<const bf16x8*>(&sB[brow * D + bcc * 8]);
            acc[ct] = __builtin_amdgcn_mfma_f32_16x16x32_bf16(a, b, acc[ct], 0, 0, 0);
        }
    }

#pragma unroll
    for (int ct = 0; ct < 8; ++ct) {
#pragma unroll
        for (int i = 0; i < 4; ++i) {
            int row = row0 + w * 16 + lq * 4 + i;
            int col = ct * 16 + lr;
            if (row < n) HWb[(size_t)row * D + col] = f2bf(acc[ct][i]);
        }
    }
}

// ---------------- pass 1: bin edges into per-bin segments ----------------
// Entry: x = (row_in_bin << 16) | col  (needs n < 65536), y = val bits.
__global__ __launch_bounds__(256) void k_bin(const int* __restrict__ rows,
                                             const int* __restrict__ cols,
                                             const float* __restrict__ vals,
                                             int* __restrict__ gcnt,
                                             int2* __restrict__ segs,
                                             int E, int nbins) {
    __shared__ int lcnt[MAXBINS];
    __shared__ int loff[MAXBINS];
    int chunk = (E + NB1 - 1) / NB1;
    int s = blockIdx.x * chunk;
    int epos = s + chunk; if (epos > E) epos = E;
    for (int i = threadIdx.x; i < nbins; i += 256) lcnt[i] = 0;
    __syncthreads();
    for (int e = s + threadIdx.x; e < epos; e += 256)
        atomicAdd(&lcnt[rows[e] >> BINSH], 1);          // int LDS atomic: HW ds_add
    __syncthreads();
    for (int i = threadIdx.x; i < nbins; i += 256) {
        int c = lcnt[i];
        int base = c ? atomicAdd(&gcnt[i * 16], c) : 0;
        loff[i] = i * CAPB + base;
        lcnt[i] = 0;                    // reuse as cursor
    }
    __syncthreads();
    for (int e = s + threadIdx.x; e < epos; e += 256) {
        int r = rows[e];
        int c = cols[e];
        float v = vals[e];
        int bin = r >> BINSH;
        int p = atomicAdd(&lcnt[bin], 1);
        int pos = loff[bin] + p;
        if (pos < (bin + 1) * CAPB)     // overflow guard (won't trigger)
            segs[pos] = make_int2(((r & 63) << 16) | c, __float_as_int(v));
    }
}

// ---------------- pass 2: per-bin row-sort in LDS + register-accum gather ----------------
// One block per 64-row bin. NO float atomics anywhere:
//  1. load bin segment -> LDS; histogram rows with int LDS atomics (HW ds_add)
//  2. 64-wide shfl scan -> per-row offsets
//  3. scatter entries into row-sorted LDS array (int cursor atomics)
//  4. wave w handles rows w, w+4, ...: entry reads are uniform-address LDS
//     (broadcast), HWb gathers 4-deep unrolled, accumulate in REGISTERS,
//     write bias+ReLU output coalesced (512B per wave).
__global__ __launch_bounds__(256) void k_spmm(const unsigned short* __restrict__ HWb,
                                              const int* __restrict__ gcnt,
                                              const int2* __restrict__ segs,
                                              const float* __restrict__ bias,
                                              float* __restrict__ out, int n) {
    __shared__ int2 ent[CAPB];      // 12KB
    __shared__ int2 sent[CAPB];     // 12KB
    __shared__ int lcnt[64];
    __shared__ int loff[64];
    __shared__ int lcur[64];
    const int b = blockIdx.x;
    int cnt = gcnt[b * 16];
    if (cnt > CAPB) cnt = CAPB;

    if (threadIdx.x < 64) lcnt[threadIdx.x] = 0;
    __syncthreads();
    for (int i = threadIdx.x; i < cnt; i += 256) {
        int2 e = segs[(size_t)b * CAPB + i];
        ent[i] = e;
        atomicAdd(&lcnt[((unsigned)e.x) >> 16], 1);
    }
    __syncthreads();
    if (threadIdx.x < 64) {
        int v = lcnt[threadIdx.x];
        int inc = v;
#pragma unroll
        for (int o = 1; o < 64; o <<= 1) {
            int t = __shfl_up(inc, o);
            if (threadIdx.x >= o) inc += t;
        }
        loff[threadIdx.x] = inc - v;
        lcur[threadIdx.x] = inc - v;
    }
    __syncthreads();
    for (int i = threadIdx.x; i < cnt; i += 256) {
        int2 e = ent[i];
        int p = atomicAdd(&lcur[((unsigned)e.x) >> 16], 1);
        sent[p] = e;
    }
    __syncthreads();

    const int w = threadIdx.x >> 6, lane = threadIdx.x & 63;
    const unsigned c2 = 2 * lane;
    const float2 bb = *reinterpret_cast<const float2*>(&bias[c2]);

    for (int rr = w; rr < 64; rr += 4) {
        int row = b * 64 + rr;
        if (row >= n) break;
        int s = loff[rr];
        int deg = lcnt[rr];
        float a0 = 0.f, a1 = 0.f, b0 = 0.f, b1 = 0.f;
        int t = 0;
        for (; t + 4 <= deg; t += 4) {
            int2 e0 = sent[s + t],     e1 = sent[s + t + 1];   // uniform addr -> broadcast
            int2 e2 = sent[s + t + 2], e3 = sent[s + t + 3];
            unsigned m0 = *reinterpret_cast<const unsigned*>(&HWb[(size_t)(e0.x & 0xFFFF) * D + c2]);
            unsigned m1 = *reinterpret_cast<const unsigned*>(&HWb[(size_t)(e1.x & 0xFFFF) * D + c2]);
            unsigned m2 = *reinterpret_cast<const unsigned*>(&HWb[(size_t)(e2.x & 0xFFFF) * D + c2]);
            unsigned m3 = *reinterpret_cast<const unsigned*>(&HWb[(size_t)(e3.x & 0xFFFF) * D + c2]);
            float v0 = __int_as_float(e0.y), v1 = __int_as_float(e1.y);
            float v2 = __int_as_float(e2.y), v3 = __int_as_float(e3.y);
            a0 += v0 * bf2f((unsigned short)(m0 & 0xFFFF));
            a1 += v0 * bf2f((unsigned short)(m0 >> 16));
            b0 += v1 * bf2f((unsigned short)(m1 & 0xFFFF));
            b1 += v1 * bf2f((unsigned short)(m1 >> 16));
            a0 += v2 * bf2f((unsigned short)(m2 & 0xFFFF));
            a1 += v2 * bf2f((unsigned short)(m2 >> 16));
            b0 += v3 * bf2f((unsigned short)(m3 & 0xFFFF));
            b1 += v3 * bf2f((unsigned short)(m3 >> 16));
        }
        for (; t < deg; ++t) {
            int2 e = sent[s + t];
            unsigned m = *reinterpret_cast<const unsigned*>(&HWb[(size_t)(e.x & 0xFFFF) * D + c2]);
            float v = __int_as_float(e.y);
            a0 += v * bf2f((unsigned short)(m & 0xFFFF));
            a1 += v * bf2f((unsigned short)(m >> 16));
        }
        float2 o;
        o.x = fmaxf(a0 + b0 + bb.x, 0.f);
        o.y = fmaxf(a1 + b1 + bb.y, 0.f);
        *reinterpret_cast<float2*>(&out[(size_t)row * D + c2]) = o;
    }
}

// ---------------- Fallback path (small ws): atomic scatter ----------------
__global__ void k_init_bias(const float* __restrict__ bias, float* __restrict__ out, int n) {
    int i = blockIdx.x * blockDim.x + threadIdx.x;
    if (i < n * D) out[i] = bias[i & (D - 1)];
}
__global__ void k_scatter(const unsigned short* __restrict__ HWb, const int* __restrict__ rows,
                          const int* __restrict__ cols, const float* __restrict__ vals,
                          float* __restrict__ out, int E) {
    int e = blockIdx.x * 2 + (threadIdx.x >> 7);
    int j = threadIdx.x & (D - 1);
    if (e < E) {
        int r = rows[e];
        int c = cols[e];
        float v = vals[e];
        atomicAdd(&out[(size_t)r * D + j], v * bf2f(HWb[(size_t)c * D + j]));
    }
}
__global__ void k_relu(float* __restrict__ out, int n) {
    int i = blockIdx.x * blockDim.x + threadIdx.x;
    if (i < n * D) out[i] = fmaxf(out[i], 0.f);
}

extern "C" void kernel_launch(void* const* d_in, const int* in_sizes, int n_in,
                              void* d_out, int out_size, void* d_ws, size_t ws_size,
                              hipStream_t stream) {
    const float* H         = (const float*)d_in[0];
    const float* W         = (const float*)d_in[1];
    const float* bias      = (const float*)d_in[2];
    const float* edge_vals = (const float*)d_in[3];
    const int*   edge_rows = (const int*)d_in[4];
    const int*   edge_cols = (const int*)d_in[5];
    float* out = (float*)d_out;

    const int n = in_sizes[0] / D;   // 50000
    const int E = in_sizes[3];       // 800000
    const int gblocks = (n + BM - 1) / BM;
    const int nbins = (n + 63) >> BINSH;   // 782

    char* ws = (char*)d_ws;
    unsigned short* HWb = (unsigned short*)ws; ws += (size_t)n * D * sizeof(unsigned short);
    unsigned short* Wt  = (unsigned short*)ws; ws += (size_t)D * D * sizeof(unsigned short);
    int* gcnt = (int*)ws;            ws += (size_t)nbins * 16 * sizeof(int);
    int2* segs = (int2*)ws;          ws += (size_t)nbins * CAPB * sizeof(int2);
    size_t need_full = (size_t)(ws - (char*)d_ws);

    k_prepw<<<D, D, 0, stream>>>(W, Wt, gcnt, nbins);
    k_gemm<<<gblocks, 256, 0, stream>>>(H, Wt, HWb, n);

    if (ws_size >= need_full && n < 65536 && nbins <= MAXBINS) {
        k_bin<<<NB1, 256, 0, stream>>>(edge_rows, edge_cols, edge_vals,
                                       gcnt, segs, E, nbins);
        k_spmm<<<nbins, 256, 0, stream>>>(HWb, gcnt, segs, bias, out, n);
    } else {
        k_init_bias<<<((size_t)n * D + 255) / 256, 256, 0, stream>>>(bias, out, n);
        k_scatter<<<(E + 1) / 2, 256, 0, stream>>>(HWb, edge_rows, edge_cols, edge_vals, out, E);
        k_relu<<<((size_t)n * D + 255) / 256, 256, 0, stream>>>(out, n);
    }
}

// Round 11
// 84.811 us; speedup vs baseline: 8.8815x; 1.0563x over previous
//
#include <hip/hip_runtime.h>

#define D 128
#define BM 64        // rows per gemm block
#define NB1 128      // binning blocks
#define BINSH 6      // 64 rows per bin
#define MAXBINS 1024
#define CAPB 1536    // entries per bin segment (avg 1023, +16 sigma)

typedef __attribute__((ext_vector_type(8))) short bf16x8;
typedef __attribute__((ext_vector_type(4))) float f32x4;

__device__ __forceinline__ unsigned short f2bf(float f) {
    unsigned u = __float_as_uint(f);
    u = (u + 0x7FFFu + ((u >> 16) & 1u)) >> 16;   // RNE
    return (unsigned short)u;
}
__device__ __forceinline__ float bf2f(unsigned short h) {
    return __uint_as_float(((unsigned)h) << 16);
}

// ---------------- prep: Wt[n][k] = bf16(W[k][n]) + zero bin counters ----------------
__global__ __launch_bounds__(128) void k_prepw(const float* __restrict__ W,
                                               unsigned short* __restrict__ Wt,
                                               int* __restrict__ gcnt, int nbins) {
    int nn = blockIdx.x, k = threadIdx.x;
    Wt[nn * D + k] = f2bf(W[k * D + nn]);
    int gtid = blockIdx.x * 128 + threadIdx.x;
    for (int i = gtid; i < nbins * 16; i += 128 * D) gcnt[i] = 0;
}

// ---------------- GEMM: HWb = bf16(bf16(H) @ bf16(W)) via MFMA ----------------
__global__ __launch_bounds__(256) void k_gemm(const float* __restrict__ H,
                                              const unsigned short* __restrict__ Wt,
                                              unsigned short* __restrict__ HWb,
                                              int n) {
    __shared__ unsigned short sA[BM * D];
    __shared__ unsigned short sB[D * D];
    const int tid = threadIdx.x;
    const int row0 = blockIdx.x * BM;

#pragma unroll
    for (int s = 0; s < 8; ++s) {
        int idx = s * 256 + tid;
        int nn = idx >> 4, cc = idx & 15;
        bf16x8 v = *reinterpret_cast<const bf16x8*>(&Wt[(size_t)idx * 8]);
        *reinterpret_cast<bf16x8*>(&sB[nn * D + ((cc ^ (nn & 7)) * 8)]) = v;
    }
#pragma unroll
    for (int s = 0; s < 4; ++s) {
        int idx = s * 256 + tid;
        int r = idx >> 4, cc = idx & 15;
        int row = row0 + r;
        float4 u0 = make_float4(0.f, 0.f, 0.f, 0.f), u1 = u0;
        if (row < n) {
            const float4* p = reinterpret_cast<const float4*>(&H[(size_t)row * D + cc * 8]);
            u0 = p[0]; u1 = p[1];
        }
        bf16x8 v;
        v[0] = (short)f2bf(u0.x); v[1] = (short)f2bf(u0.y);
        v[2] = (short)f2bf(u0.z); v[3] = (short)f2bf(u0.w);
        v[4] = (short)f2bf(u1.x); v[5] = (short)f2bf(u1.y);
        v[6] = (short)f2bf(u1.z); v[7] = (short)f2bf(u1.w);
        *reinterpret_cast<bf16x8*>(&sA[r * D + ((cc ^ (r & 7)) * 8)]) = v;
    }
    __syncthreads();

    const int w = tid >> 6, l = tid & 63;
    const int lr = l & 15, lq = l >> 4;
    f32x4 acc[8];
#pragma unroll
    for (int ct = 0; ct < 8; ++ct) acc[ct] = (f32x4){0.f, 0.f, 0.f, 0.f};

#pragma unroll
    for (int ks = 0; ks < 4; ++ks) {
        const int arow = w * 16 + lr;
        const int acc_c = (ks * 4 + lq) ^ (arow & 7);
        bf16x8 a = *reinterpret_cast<const bf16x8*>(&sA[arow * D + acc_c * 8]);
#pragma unroll
        for (int ct = 0; ct < 8; ++ct) {
            const int brow = ct * 16 + lr;
            const int bcc = (ks * 4 + lq) ^ (brow & 7);
            bf16x8 b = *reinterpret_cast<const bf16x8*>(&sB[brow * D + bcc * 8]);
            acc[ct] = __builtin_amdgcn_mfma_f32_16x16x32_bf16(a, b, acc[ct], 0, 0, 0);
        }
    }

#pragma unroll
    for (int ct = 0; ct < 8; ++ct) {
#pragma unroll
        for (int i = 0; i < 4; ++i) {
            int row = row0 + w * 16 + lq * 4 + i;
            int col = ct * 16 + lr;
            if (row < n) HWb[(size_t)row * D + col] = f2bf(acc[ct][i]);
        }
    }
}

// ---------------- pass 1: bin edges into per-bin segments ----------------
// Entry: x = (row_in_bin << 16) | col  (needs n < 65536), y = val bits.
__global__ __launch_bounds__(256) void k_bin(const int* __restrict__ rows,
                                             const int* __restrict__ cols,
                                             const float* __restrict__ vals,
                                             int* __restrict__ gcnt,
                                             int2* __restrict__ segs,
                                             int E, int nbins) {
    __shared__ int lcnt[MAXBINS];
    __shared__ int loff[MAXBINS];
    int chunk = (E + NB1 - 1) / NB1;
    int s = blockIdx.x * chunk;
    int epos = s + chunk; if (epos > E) epos = E;
    for (int i = threadIdx.x; i < nbins; i += 256) lcnt[i] = 0;
    __syncthreads();
    for (int e = s + threadIdx.x; e < epos; e += 256)
        atomicAdd(&lcnt[rows[e] >> BINSH], 1);          // int LDS atomic: HW ds_add
    __syncthreads();
    for (int i = threadIdx.x; i < nbins; i += 256) {
        int c = lcnt[i];
        int base = c ? atomicAdd(&gcnt[i * 16], c) : 0;
        loff[i] = i * CAPB + base;
        lcnt[i] = 0;                    // reuse as cursor
    }
    __syncthreads();
    for (int e = s + threadIdx.x; e < epos; e += 256) {
        int r = rows[e];
        int c = cols[e];
        float v = vals[e];
        int bin = r >> BINSH;
        int p = atomicAdd(&lcnt[bin], 1);
        int pos = loff[bin] + p;
        if (pos < (bin + 1) * CAPB)     // overflow guard (won't trigger)
            segs[pos] = make_int2(((r & 63) << 16) | c, __float_as_int(v));
    }
}

// ---------------- pass 2: per-bin row-sort in LDS + register-accum gather ----------------
// 512 threads = 8 waves; wave w handles rows w, w+8, ... (8 rows each).
// 1. histogram rows straight from the global segment (coalesced, L2-hot)
// 2. 64-wide shfl scan -> per-row offsets
// 3. re-read segment, scatter row-sorted into LDS (int cursor atomics)
// 4. per-row gather: uniform-address LDS entry reads (broadcast), 8-deep
//    unrolled HWb gathers, register accumulate, coalesced bias+ReLU store.
__global__ __launch_bounds__(512) void k_spmm(const unsigned short* __restrict__ HWb,
                                              const int* __restrict__ gcnt,
                                              const int2* __restrict__ segs,
                                              const float* __restrict__ bias,
                                              float* __restrict__ out, int n) {
    __shared__ int2 sent[CAPB];     // 12KB
    __shared__ int lcnt[64];
    __shared__ int loff[64];
    __shared__ int lcur[64];
    const int b = blockIdx.x;
    int cnt = gcnt[b * 16];
    if (cnt > CAPB) cnt = CAPB;
    const int2* seg = segs + (size_t)b * CAPB;

    if (threadIdx.x < 64) lcnt[threadIdx.x] = 0;
    __syncthreads();
    for (int i = threadIdx.x; i < cnt; i += 512)
        atomicAdd(&lcnt[((unsigned)seg[i].x) >> 16], 1);
    __syncthreads();
    if (threadIdx.x < 64) {
        int v = lcnt[threadIdx.x];
        int inc = v;
#pragma unroll
        for (int o = 1; o < 64; o <<= 1) {
            int t = __shfl_up(inc, o);
            if (threadIdx.x >= o) inc += t;
        }
        loff[threadIdx.x] = inc - v;
        lcur[threadIdx.x] = inc - v;
    }
    __syncthreads();
    for (int i = threadIdx.x; i < cnt; i += 512) {
        int2 e = seg[i];
        int p = atomicAdd(&lcur[((unsigned)e.x) >> 16], 1);
        sent[p] = e;
    }
    __syncthreads();

    const int w = threadIdx.x >> 6, lane = threadIdx.x & 63;
    const unsigned c2 = 2 * lane;
    const float2 bb = *reinterpret_cast<const float2*>(&bias[c2]);

    for (int rr = w; rr < 64; rr += 8) {
        int row = b * 64 + rr;
        if (row >= n) break;
        int s = loff[rr];
        int deg = lcnt[rr];
        float a0 = 0.f, a1 = 0.f, b0 = 0.f, b1 = 0.f;
        int t = 0;
        for (; t + 8 <= deg; t += 8) {
            int2 e0 = sent[s + t],     e1 = sent[s + t + 1];   // uniform addr -> broadcast
            int2 e2 = sent[s + t + 2], e3 = sent[s + t + 3];
            int2 e4 = sent[s + t + 4], e5 = sent[s + t + 5];
            int2 e6 = sent[s + t + 6], e7 = sent[s + t + 7];
            unsigned m0 = *reinterpret_cast<const unsigned*>(&HWb[(size_t)(e0.x & 0xFFFF) * D + c2]);
            unsigned m1 = *reinterpret_cast<const unsigned*>(&HWb[(size_t)(e1.x & 0xFFFF) * D + c2]);
            unsigned m2 = *reinterpret_cast<const unsigned*>(&HWb[(size_t)(e2.x & 0xFFFF) * D + c2]);
            unsigned m3 = *reinterpret_cast<const unsigned*>(&HWb[(size_t)(e3.x & 0xFFFF) * D + c2]);
            unsigned m4 = *reinterpret_cast<const unsigned*>(&HWb[(size_t)(e4.x & 0xFFFF) * D + c2]);
            unsigned m5 = *reinterpret_cast<const unsigned*>(&HWb[(size_t)(e5.x & 0xFFFF) * D + c2]);
            unsigned m6 = *reinterpret_cast<const unsigned*>(&HWb[(size_t)(e6.x & 0xFFFF) * D + c2]);
            unsigned m7 = *reinterpret_cast<const unsigned*>(&HWb[(size_t)(e7.x & 0xFFFF) * D + c2]);
            float v0 = __int_as_float(e0.y), v1 = __int_as_float(e1.y);
            float v2 = __int_as_float(e2.y), v3 = __int_as_float(e3.y);
            float v4 = __int_as_float(e4.y), v5 = __int_as_float(e5.y);
            float v6 = __int_as_float(e6.y), v7 = __int_as_float(e7.y);
            a0 += v0 * bf2f((unsigned short)(m0 & 0xFFFF));
            a1 += v0 * bf2f((unsigned short)(m0 >> 16));
            b0 += v1 * bf2f((unsigned short)(m1 & 0xFFFF));
            b1 += v1 * bf2f((unsigned short)(m1 >> 16));
            a0 += v2 * bf2f((unsigned short)(m2 & 0xFFFF));
            a1 += v2 * bf2f((unsigned short)(m2 >> 16));
            b0 += v3 * bf2f((unsigned short)(m3 & 0xFFFF));
            b1 += v3 * bf2f((unsigned short)(m3 >> 16));
            a0 += v4 * bf2f((unsigned short)(m4 & 0xFFFF));
            a1 += v4 * bf2f((unsigned short)(m4 >> 16));
            b0 += v5 * bf2f((unsigned short)(m5 & 0xFFFF));
            b1 += v5 * bf2f((unsigned short)(m5 >> 16));
            a0 += v6 * bf2f((unsigned short)(m6 & 0xFFFF));
            a1 += v6 * bf2f((unsigned short)(m6 >> 16));
            b0 += v7 * bf2f((unsigned short)(m7 & 0xFFFF));
            b1 += v7 * bf2f((unsigned short)(m7 >> 16));
        }
        for (; t < deg; ++t) {
            int2 e = sent[s + t];
            unsigned m = *reinterpret_cast<const unsigned*>(&HWb[(size_t)(e.x & 0xFFFF) * D + c2]);
            float v = __int_as_float(e.y);
            a0 += v * bf2f((unsigned short)(m & 0xFFFF));
            a1 += v * bf2f((unsigned short)(m >> 16));
        }
        float2 o;
        o.x = fmaxf(a0 + b0 + bb.x, 0.f);
        o.y = fmaxf(a1 + b1 + bb.y, 0.f);
        *reinterpret_cast<float2*>(&out[(size_t)row * D + c2]) = o;
    }
}

// ---------------- Fallback path (small ws): atomic scatter ----------------
__global__ void k_init_bias(const float* __restrict__ bias, float* __restrict__ out, int n) {
    int i = blockIdx.x * blockDim.x + threadIdx.x;
    if (i < n * D) out[i] = bias[i & (D - 1)];
}
__global__ void k_scatter(const unsigned short* __restrict__ HWb, const int* __restrict__ rows,
                          const int* __restrict__ cols, const float* __restrict__ vals,
                          float* __restrict__ out, int E) {
    int e = blockIdx.x * 2 + (threadIdx.x >> 7);
    int j = threadIdx.x & (D - 1);
    if (e < E) {
        int r = rows[e];
        int c = cols[e];
        float v = vals[e];
        atomicAdd(&out[(size_t)r * D + j], v * bf2f(HWb[(size_t)c * D + j]));
    }
}
__global__ void k_relu(float* __restrict__ out, int n) {
    int i = blockIdx.x * blockDim.x + threadIdx.x;
    if (i < n * D) out[i] = fmaxf(out[i], 0.f);
}

extern "C" void kernel_launch(void* const* d_in, const int* in_sizes, int n_in,
                              void* d_out, int out_size, void* d_ws, size_t ws_size,
                              hipStream_t stream) {
    const float* H         = (const float*)d_in[0];
    const float* W         = (const float*)d_in[1];
    const float* bias      = (const float*)d_in[2];
    const float* edge_vals = (const float*)d_in[3];
    const int*   edge_rows = (const int*)d_in[4];
    const int*   edge_cols = (const int*)d_in[5];
    float* out = (float*)d_out;

    const int n = in_sizes[0] / D;   // 50000
    const int E = in_sizes[3];       // 800000
    const int gblocks = (n + BM - 1) / BM;
    const int nbins = (n + 63) >> BINSH;   // 782

    char* ws = (char*)d_ws;
    unsigned short* HWb = (unsigned short*)ws; ws += (size_t)n * D * sizeof(unsigned short);
    unsigned short* Wt  = (unsigned short*)ws; ws += (size_t)D * D * sizeof(unsigned short);
    int* gcnt = (int*)ws;            ws += (size_t)nbins * 16 * sizeof(int);
    int2* segs = (int2*)ws;          ws += (size_t)nbins * CAPB * sizeof(int2);
    size_t need_full = (size_t)(ws - (char*)d_ws);

    k_prepw<<<D, D, 0, stream>>>(W, Wt, gcnt, nbins);
    k_gemm<<<gblocks, 256, 0, stream>>>(H, Wt, HWb, n);

    if (ws_size >= need_full && n < 65536 && nbins <= MAXBINS) {
        k_bin<<<NB1, 256, 0, stream>>>(edge_rows, edge_cols, edge_vals,
                                       gcnt, segs, E, nbins);
        k_spmm<<<nbins, 512, 0, stream>>>(HWb, gcnt, segs, bias, out, n);
    } else {
        k_init_bias<<<((size_t)n * D + 255) / 256, 256, 0, stream>>>(bias, out, n);
        k_scatter<<<(E + 1) / 2, 256, 0, stream>>>(HWb, edge_rows, edge_cols, edge_vals, out, E);
        k_relu<<<((size_t)n * D + 255) / 256, 256, 0, stream>>>(out, n);
    }
}

// Round 12
// 73.585 us; speedup vs baseline: 10.2364x; 1.1525x over previous
//
#include <hip/hip_runtime.h>

#define D 128
#define BM 64        // rows per gemm block
#define NBB 256      // binning blocks (subset of gemm grid)
#define BINSH 6      // 64 rows per bin
#define MAXBINS 1024
#define CAPB 1536    // entries per bin segment (avg 1023, +16 sigma)

typedef __attribute__((ext_vector_type(8))) short bf16x8;
typedef __attribute__((ext_vector_type(4))) float f32x4;

__device__ __forceinline__ unsigned short f2bf(float f) {
    unsigned u = __float_as_uint(f);
    u = (u + 0x7FFFu + ((u >> 16) & 1u)) >> 16;   // RNE
    return (unsigned short)u;
}
__device__ __forceinline__ float bf2f(unsigned short h) {
    return __uint_as_float(((unsigned)h) << 16);
}

// ---------------- prep: Wt[n][k] = bf16(W[k][n]) + zero bin counters ----------------
__global__ __launch_bounds__(128) void k_prepw(const float* __restrict__ W,
                                               unsigned short* __restrict__ Wt,
                                               int* __restrict__ gcnt, int nbins) {
    int nn = blockIdx.x, k = threadIdx.x;
    Wt[nn * D + k] = f2bf(W[k * D + nn]);
    int gtid = blockIdx.x * 128 + threadIdx.x;
    for (int i = gtid; i < nbins * 16; i += 128 * D) gcnt[i] = 0;
}

// ---------------- fused GEMM + edge binning ----------------
// gemm part: HWb = bf16(bf16(H) @ bf16(W)) via MFMA, 64-row tiles.
// bin part (blocks 0..NBB-1, AFTER the gemm epilogue, LDS reused): bin edges
// into per-bin segments; entry x = (row_in_bin<<16)|col (needs n<65536).
// The bin pass of 256 blocks overlaps the remaining blocks' gemm compute.
__global__ __launch_bounds__(256) void k_gemm_bin(const float* __restrict__ H,
                                                  const unsigned short* __restrict__ Wt,
                                                  unsigned short* __restrict__ HWb,
                                                  int n,
                                                  const int* __restrict__ rows,
                                                  const int* __restrict__ cols,
                                                  const float* __restrict__ vals,
                                                  int* __restrict__ gcnt,
                                                  int2* __restrict__ segs,
                                                  int E, int nbins, int nbb) {
    __shared__ unsigned short sA[BM * D];     // 16KB (reused by bin phase)
    __shared__ unsigned short sB[D * D];      // 32KB
    const int tid = threadIdx.x;
    const int row0 = blockIdx.x * BM;

#pragma unroll
    for (int s = 0; s < 8; ++s) {
        int idx = s * 256 + tid;
        int nn = idx >> 4, cc = idx & 15;
        bf16x8 v = *reinterpret_cast<const bf16x8*>(&Wt[(size_t)idx * 8]);
        *reinterpret_cast<bf16x8*>(&sB[nn * D + ((cc ^ (nn & 7)) * 8)]) = v;
    }
#pragma unroll
    for (int s = 0; s < 4; ++s) {
        int idx = s * 256 + tid;
        int r = idx >> 4, cc = idx & 15;
        int row = row0 + r;
        float4 u0 = make_float4(0.f, 0.f, 0.f, 0.f), u1 = u0;
        if (row < n) {
            const float4* p = reinterpret_cast<const float4*>(&H[(size_t)row * D + cc * 8]);
            u0 = p[0]; u1 = p[1];
        }
        bf16x8 v;
        v[0] = (short)f2bf(u0.x); v[1] = (short)f2bf(u0.y);
        v[2] = (short)f2bf(u0.z); v[3] = (short)f2bf(u0.w);
        v[4] = (short)f2bf(u1.x); v[5] = (short)f2bf(u1.y);
        v[6] = (short)f2bf(u1.z); v[7] = (short)f2bf(u1.w);
        *reinterpret_cast<bf16x8*>(&sA[r * D + ((cc ^ (r & 7)) * 8)]) = v;
    }
    __syncthreads();

    const int w = tid >> 6, l = tid & 63;
    const int lr = l & 15, lq = l >> 4;
    f32x4 acc[8];
#pragma unroll
    for (int ct = 0; ct < 8; ++ct) acc[ct] = (f32x4){0.f, 0.f, 0.f, 0.f};

#pragma unroll
    for (int ks = 0; ks < 4; ++ks) {
        const int arow = w * 16 + lr;
        const int acc_c = (ks * 4 + lq) ^ (arow & 7);
        bf16x8 a = *reinterpret_cast<const bf16x8*>(&sA[arow * D + acc_c * 8]);
#pragma unroll
        for (int ct = 0; ct < 8; ++ct) {
            const int brow = ct * 16 + lr;
            const int bcc = (ks * 4 + lq) ^ (brow & 7);
            bf16x8 b = *reinterpret_cast<const bf16x8*>(&sB[brow * D + bcc * 8]);
            acc[ct] = __builtin_amdgcn_mfma_f32_16x16x32_bf16(a, b, acc[ct], 0, 0, 0);
        }
    }

#pragma unroll
    for (int ct = 0; ct < 8; ++ct) {
#pragma unroll
        for (int i = 0; i < 4; ++i) {
            int row = row0 + w * 16 + lq * 4 + i;
            int col = ct * 16 + lr;
            if (row < n) HWb[(size_t)row * D + col] = f2bf(acc[ct][i]);
        }
    }

    // ---------------- bin phase (first nbb blocks only) ----------------
    if (blockIdx.x < (unsigned)nbb) {
        __syncthreads();                       // all waves done with sA
        int* lcnt = reinterpret_cast<int*>(sA);          // 4KB of 16KB
        int* loff = lcnt + MAXBINS;                      // next 4KB
        int chunk = (E + nbb - 1) / nbb;
        int s = blockIdx.x * chunk;
        int epos = s + chunk; if (epos > E) epos = E;
        for (int i = tid; i < nbins; i += 256) lcnt[i] = 0;
        __syncthreads();
        for (int e = s + tid; e < epos; e += 256)
            atomicAdd(&lcnt[rows[e] >> BINSH], 1);       // HW ds_add
        __syncthreads();
        for (int i = tid; i < nbins; i += 256) {
            int c = lcnt[i];
            int base = c ? atomicAdd(&gcnt[i * 16], c) : 0;
            loff[i] = i * CAPB + base;
            lcnt[i] = 0;                                 // reuse as cursor
        }
        __syncthreads();
        for (int e = s + tid; e < epos; e += 256) {
            int r = rows[e];
            int c = cols[e];
            float v = vals[e];
            int bin = r >> BINSH;
            int p = atomicAdd(&lcnt[bin], 1);
            int pos = loff[bin] + p;
            if (pos < (bin + 1) * CAPB)                  // overflow guard
                segs[pos] = make_int2(((r & 63) << 16) | c, __float_as_int(v));
        }
    }
}

// ---------------- pass 2: per-bin row-sort in LDS + register-accum gather ----------------
// 512 threads = 8 waves. Segment is read from global ONCE into registers
// (3 entries/thread = CAPB); histogram + row-sorted scatter run from registers.
// Wave w handles rows w, w+8, ...: uniform-address LDS entry reads (broadcast),
// 8-deep unrolled HWb gathers, register accumulate, coalesced bias+ReLU store.
__global__ __launch_bounds__(512) void k_spmm(const unsigned short* __restrict__ HWb,
                                              const int* __restrict__ gcnt,
                                              const int2* __restrict__ segs,
                                              const float* __restrict__ bias,
                                              float* __restrict__ out, int n) {
    __shared__ int2 sent[CAPB];     // 12KB
    __shared__ int lcnt[64];
    __shared__ int loff[64];
    __shared__ int lcur[64];
    const int b = blockIdx.x;
    int cnt = gcnt[b * 16];
    if (cnt > CAPB) cnt = CAPB;
    const int2* seg = segs + (size_t)b * CAPB;

    if (threadIdx.x < 64) lcnt[threadIdx.x] = 0;
    __syncthreads();
    int2 er[3];
#pragma unroll
    for (int k = 0; k < 3; ++k) {
        int i = threadIdx.x + k * 512;
        if (i < cnt) {
            er[k] = seg[i];
            atomicAdd(&lcnt[((unsigned)er[k].x) >> 16], 1);
        }
    }
    __syncthreads();
    if (threadIdx.x < 64) {
        int v = lcnt[threadIdx.x];
        int inc = v;
#pragma unroll
        for (int o = 1; o < 64; o <<= 1) {
            int t = __shfl_up(inc, o);
            if (threadIdx.x >= o) inc += t;
        }
        loff[threadIdx.x] = inc - v;
        lcur[threadIdx.x] = inc - v;
    }
    __syncthreads();
#pragma unroll
    for (int k = 0; k < 3; ++k) {
        int i = threadIdx.x + k * 512;
        if (i < cnt) {
            int p = atomicAdd(&lcur[((unsigned)er[k].x) >> 16], 1);
            sent[p] = er[k];
        }
    }
    __syncthreads();

    const int w = threadIdx.x >> 6, lane = threadIdx.x & 63;
    const unsigned c2 = 2 * lane;
    const float2 bb = *reinterpret_cast<const float2*>(&bias[c2]);

    for (int rr = w; rr < 64; rr += 8) {
        int row = b * 64 + rr;
        if (row >= n) break;
        int s = loff[rr];
        int deg = lcnt[rr];
        float a0 = 0.f, a1 = 0.f, b0 = 0.f, b1 = 0.f;
        int t = 0;
        for (; t + 8 <= deg; t += 8) {
            int2 e0 = sent[s + t],     e1 = sent[s + t + 1];   // uniform addr -> broadcast
            int2 e2 = sent[s + t + 2], e3 = sent[s + t + 3];
            int2 e4 = sent[s + t + 4], e5 = sent[s + t + 5];
            int2 e6 = sent[s + t + 6], e7 = sent[s + t + 7];
            unsigned m0 = *reinterpret_cast<const unsigned*>(&HWb[(size_t)(e0.x & 0xFFFF) * D + c2]);
            unsigned m1 = *reinterpret_cast<const unsigned*>(&HWb[(size_t)(e1.x & 0xFFFF) * D + c2]);
            unsigned m2 = *reinterpret_cast<const unsigned*>(&HWb[(size_t)(e2.x & 0xFFFF) * D + c2]);
            unsigned m3 = *reinterpret_cast<const unsigned*>(&HWb[(size_t)(e3.x & 0xFFFF) * D + c2]);
            unsigned m4 = *reinterpret_cast<const unsigned*>(&HWb[(size_t)(e4.x & 0xFFFF) * D + c2]);
            unsigned m5 = *reinterpret_cast<const unsigned*>(&HWb[(size_t)(e5.x & 0xFFFF) * D + c2]);
            unsigned m6 = *reinterpret_cast<const unsigned*>(&HWb[(size_t)(e6.x & 0xFFFF) * D + c2]);
            unsigned m7 = *reinterpret_cast<const unsigned*>(&HWb[(size_t)(e7.x & 0xFFFF) * D + c2]);
            float v0 = __int_as_float(e0.y), v1 = __int_as_float(e1.y);
            float v2 = __int_as_float(e2.y), v3 = __int_as_float(e3.y);
            float v4 = __int_as_float(e4.y), v5 = __int_as_float(e5.y);
            float v6 = __int_as_float(e6.y), v7 = __int_as_float(e7.y);
            a0 += v0 * bf2f((unsigned short)(m0 & 0xFFFF));
            a1 += v0 * bf2f((unsigned short)(m0 >> 16));
            b0 += v1 * bf2f((unsigned short)(m1 & 0xFFFF));
            b1 += v1 * bf2f((unsigned short)(m1 >> 16));
            a0 += v2 * bf2f((unsigned short)(m2 & 0xFFFF));
            a1 += v2 * bf2f((unsigned short)(m2 >> 16));
            b0 += v3 * bf2f((unsigned short)(m3 & 0xFFFF));
            b1 += v3 * bf2f((unsigned short)(m3 >> 16));
            a0 += v4 * bf2f((unsigned short)(m4 & 0xFFFF));
            a1 += v4 * bf2f((unsigned short)(m4 >> 16));
            b0 += v5 * bf2f((unsigned short)(m5 & 0xFFFF));
            b1 += v5 * bf2f((unsigned short)(m5 >> 16));
            a0 += v6 * bf2f((unsigned short)(m6 & 0xFFFF));
            a1 += v6 * bf2f((unsigned short)(m6 >> 16));
            b0 += v7 * bf2f((unsigned short)(m7 & 0xFFFF));
            b1 += v7 * bf2f((unsigned short)(m7 >> 16));
        }
        for (; t < deg; ++t) {
            int2 e = sent[s + t];
            unsigned m = *reinterpret_cast<const unsigned*>(&HWb[(size_t)(e.x & 0xFFFF) * D + c2]);
            float v = __int_as_float(e.y);
            a0 += v * bf2f((unsigned short)(m & 0xFFFF));
            a1 += v * bf2f((unsigned short)(m >> 16));
        }
        float2 o;
        o.x = fmaxf(a0 + b0 + bb.x, 0.f);
        o.y = fmaxf(a1 + b1 + bb.y, 0.f);
        *reinterpret_cast<float2*>(&out[(size_t)row * D + c2]) = o;
    }
}

// ---------------- Fallback path (small ws): atomic scatter ----------------
__global__ void k_init_bias(const float* __restrict__ bias, float* __restrict__ out, int n) {
    int i = blockIdx.x * blockDim.x + threadIdx.x;
    if (i < n * D) out[i] = bias[i & (D - 1)];
}
__global__ void k_scatter(const unsigned short* __restrict__ HWb, const int* __restrict__ rows,
                          const int* __restrict__ cols, const float* __restrict__ vals,
                          float* __restrict__ out, int E) {
    int e = blockIdx.x * 2 + (threadIdx.x >> 7);
    int j = threadIdx.x & (D - 1);
    if (e < E) {
        int r = rows[e];
        int c = cols[e];
        float v = vals[e];
        atomicAdd(&out[(size_t)r * D + j], v * bf2f(HWb[(size_t)c * D + j]));
    }
}
__global__ void k_relu(float* __restrict__ out, int n) {
    int i = blockIdx.x * blockDim.x + threadIdx.x;
    if (i < n * D) out[i] = fmaxf(out[i], 0.f);
}

extern "C" void kernel_launch(void* const* d_in, const int* in_sizes, int n_in,
                              void* d_out, int out_size, void* d_ws, size_t ws_size,
                              hipStream_t stream) {
    const float* H         = (const float*)d_in[0];
    const float* W         = (const float*)d_in[1];
    const float* bias      = (const float*)d_in[2];
    const float* edge_vals = (const float*)d_in[3];
    const int*   edge_rows = (const int*)d_in[4];
    const int*   edge_cols = (const int*)d_in[5];
    float* out = (float*)d_out;

    const int n = in_sizes[0] / D;   // 50000
    const int E = in_sizes[3];       // 800000
    const int gblocks = (n + BM - 1) / BM;
    const int nbins = (n + 63) >> BINSH;   // 782
    const int nbb = (gblocks < NBB) ? gblocks : NBB;

    char* ws = (char*)d_ws;
    unsigned short* HWb = (unsigned short*)ws; ws += (size_t)n * D * sizeof(unsigned short);
    unsigned short* Wt  = (unsigned short*)ws; ws += (size_t)D * D * sizeof(unsigned short);
    int* gcnt = (int*)ws;            ws += (size_t)nbins * 16 * sizeof(int);
    int2* segs = (int2*)ws;          ws += (size_t)nbins * CAPB * sizeof(int2);
    size_t need_full = (size_t)(ws - (char*)d_ws);

    k_prepw<<<D, D, 0, stream>>>(W, Wt, gcnt, nbins);

    if (ws_size >= need_full && n < 65536 && nbins <= MAXBINS) {
        k_gemm_bin<<<gblocks, 256, 0, stream>>>(H, Wt, HWb, n,
                                                edge_rows, edge_cols, edge_vals,
                                                gcnt, segs, E, nbins, nbb);
        k_spmm<<<nbins, 512, 0, stream>>>(HWb, gcnt, segs, bias, out, n);
    } else {
        k_gemm_bin<<<gblocks, 256, 0, stream>>>(H, Wt, HWb, n,
                                                edge_rows, edge_cols, edge_vals,
                                                (int*)d_ws, (int2*)d_ws, 0, nbins, 0);
        k_init_bias<<<((size_t)n * D + 255) / 256, 256, 0, stream>>>(bias, out, n);
        k_scatter<<<(E + 1) / 2, 256, 0, stream>>>(HWb, edge_rows, edge_cols, edge_vals, out, E);
        k_relu<<<((size_t)n * D + 255) / 256, 256, 0, stream>>>(out, n);
    }
}